// Round 8
// baseline (702.113 us; speedup 1.0000x reference)
//
#include <hip/hip_runtime.h>

// ---------------------------------------------------------------------------
// GAT_L3: 3x (GATConv -> BatchNorm -> ReLU), N=50000, E=800000 (+N self-loops).
// r24 POST-MORTEM: full-OUTF blocking -> VGPR 176, crossed the 128-VGPR
// occupancy cliff (waves/CU halved) -> fused 63->106us despite FETCH 28->16MB.
// Lesson: this GEMM is latency-bound; occupancy >= LDS-intensity. Reverted to
// r23 GEMM (head-split, VGPR 104, 62us).
// Round 25 (this): bn_final fused into node_sg via last-block pattern
// (threadfence + atomic counter; last block reduces 128 partial slots,
// computes scale/shift, re-zeros partials). Removes 3 serial 1-block
// dispatches + launch gaps from the critical path.
// Predict: total 293 -> 275-285us. If >=290, launch overhead exonerated ->
// next target is node_sg internals.
// ---------------------------------------------------------------------------

__device__ __forceinline__ float lrelu(float x) { return x > 0.f ? x : 0.2f * x; }
__device__ __forceinline__ unsigned short f2bf(float x) {
    unsigned u = __float_as_uint(x);
    return (unsigned short)((u + 0x7FFFu + ((u >> 16) & 1u)) >> 16);
}
__device__ __forceinline__ float bf2f(unsigned short v) {
    return __uint_as_float(((unsigned)v) << 16);
}

// ---------------------------------------------------------------------------
// Tiled GEMM + attention epilogue body (r23 structure: head-split, depth-1
// register prefetch, unroll-1 K-loop; VGPR ~104, 4 waves/SIMD).
// ---------------------------------------------------------------------------
template <int K, int OUTF, int H, bool FUSE>
__device__ __forceinline__ void gemm_attn_body(
    int vbid, const float* __restrict__ in, const float* __restrict__ W,
    const float* __restrict__ scale, const float* __restrict__ shift,
    const float* __restrict__ a_src, const float* __restrict__ a_dst,
    unsigned short* __restrict__ hb, float* __restrict__ es,
    float* __restrict__ ed, int N)
{
    constexpr int BK = 32;
    constexpr int M = 128;
    constexpr int XS = BK + 4;
    constexpr int HS = OUTF / 32;
    constexpr int NC = K / BK;            // K-tiles: 4 (K=128) or 2 (K=64)
    __shared__ float xs[M * XS];
    __shared__ float wsl[32 * XS];
    __shared__ float redS[8 * 132];
    __shared__ float redD[8 * 132];

    const int tid = threadIdx.x;
    const int tile = (HS == 2) ? (vbid >> 1) : vbid;
    const int hs = (HS == 2) ? (vbid & 1) : 0;
    const int n0 = tile * M;
    const int jb = hs * 32;

    const int lane = tid & 31;
    const int jt = (tid >> 5) * 4;
    const int kq4 = (tid & 7) * 4;        // x-stage k-subcolumn
    const int nrow = tid >> 3;            // x-stage base row (i adds 32)
    const int wj = tid & 31;              // W-stage col
    const int wk = tid >> 5;              // W-stage base k (i adds 8)

    float acc[4][4];
#pragma unroll
    for (int i = 0; i < 4; ++i)
#pragma unroll
        for (int jj = 0; jj < 4; ++jj) acc[i][jj] = 0.f;

    // depth-1 register prefetch buffers
    float4 xr[4];
    float wr[4];

    // prologue: K-tile 0 -> regs
#pragma unroll
    for (int i = 0; i < 4; ++i) {
        int gn = n0 + nrow + 32 * i;
        if (gn >= N) gn = N - 1;
        xr[i] = *(const float4*)(in + (size_t)gn * K + kq4);
    }
#pragma unroll
    for (int i = 0; i < 4; ++i)
        wr[i] = W[(size_t)(wk + 8 * i) * OUTF + jb + wj];

#pragma unroll 1
    for (int c = 0; c < NC; ++c) {
        const int kc = c * BK;
        float4 sc, sh;
        if constexpr (FUSE) {            // column kq4 fixed for this thread
            sc = *(const float4*)(scale + kc + kq4);
            sh = *(const float4*)(shift + kc + kq4);
        }
        __syncthreads();   // previous compute done; LDS safe to overwrite
        // regs -> LDS (BN+ReLU applied here on the FUSE path)
#pragma unroll
        for (int i = 0; i < 4; ++i) {
            float4 v = xr[i];
            if constexpr (FUSE) {
                v.x = fmaxf(v.x * sc.x + sh.x, 0.f);
                v.y = fmaxf(v.y * sc.y + sh.y, 0.f);
                v.z = fmaxf(v.z * sc.z + sh.z, 0.f);
                v.w = fmaxf(v.w * sc.w + sh.w, 0.f);
            }
            *(float4*)&xs[(nrow + 32 * i) * XS + kq4] = v;
        }
#pragma unroll
        for (int i = 0; i < 4; ++i)
            wsl[wj * XS + wk + 8 * i] = wr[i];
        __syncthreads();   // staged tile visible
        // prefetch NEXT K-tile into regs; loads fly during compute below
        if (c + 1 < NC) {
            const int kn = kc + BK;
#pragma unroll
            for (int i = 0; i < 4; ++i) {
                int gn = n0 + nrow + 32 * i;
                if (gn >= N) gn = N - 1;
                xr[i] = *(const float4*)(in + (size_t)gn * K + kn + kq4);
            }
#pragma unroll
            for (int i = 0; i < 4; ++i)
                wr[i] = W[(size_t)(kn + wk + 8 * i) * OUTF + jb + wj];
        }
        // compute on staged tile
#pragma unroll
        for (int k4 = 0; k4 < BK; k4 += 4) {
            float4 xv[4];
#pragma unroll
            for (int i = 0; i < 4; ++i)
                xv[i] = *(float4*)&xs[(lane + 32 * i) * XS + k4];
#pragma unroll
            for (int jj = 0; jj < 4; ++jj) {
                float4 wv = *(float4*)&wsl[(jt + jj) * XS + k4];
#pragma unroll
                for (int i = 0; i < 4; ++i)
                    acc[i][jj] += xv[i].x * wv.x + xv[i].y * wv.y
                                + xv[i].z * wv.z + xv[i].w * wv.w;
            }
        }
    }

    const int jg = tid >> 5;
#pragma unroll
    for (int i = 0; i < 4; ++i) {
        int r = lane + 32 * i;
        int gn = n0 + r;
        float p = 0.f, q = 0.f;
#pragma unroll
        for (int jj = 0; jj < 4; ++jj) {
            p += acc[i][jj] * a_src[jb + jt + jj];
            q += acc[i][jj] * a_dst[jb + jt + jj];
        }
        if (gn < N) {
            uint2 u;
            u.x = (unsigned)f2bf(acc[i][0]) | ((unsigned)f2bf(acc[i][1]) << 16);
            u.y = (unsigned)f2bf(acc[i][2]) | ((unsigned)f2bf(acc[i][3]) << 16);
            *(uint2*)(hb + (size_t)gn * OUTF + jb + jt) = u;
        }
        redS[jg * 132 + r] = p;
        redD[jg * 132 + r] = q;
    }
    __syncthreads();
    if (tid < M) {
        int gn = n0 + tid;
        if (gn < N) {
            float e = 0.f, d = 0.f;
#pragma unroll
            for (int g = 0; g < 8; ++g) {
                e += redS[g * 132 + tid];
                d += redD[g * 132 + tid];
            }
            es[gn * H + hs] = e;
            ed[gn * H + hs] = d;
        }
    }
}

template <int K, int OUTF, int H, bool FUSE>
__global__ __launch_bounds__(256) void gemm_attn_k(
    const float* __restrict__ in, const float* __restrict__ W,
    const float* __restrict__ scale, const float* __restrict__ shift,
    const float* __restrict__ a_src, const float* __restrict__ a_dst,
    unsigned short* __restrict__ hb, float* __restrict__ es,
    float* __restrict__ ed, int N)
{
    gemm_attn_body<K, OUTF, H, FUSE>(blockIdx.x, in, W, scale, shift,
                                     a_src, a_dst, hb, es, ed, N);
}

// Fused: first GB blocks run layer-1 gemm (seed every CU); rest do the ELL
// scatter. Scatter: 8 edges/thread (2048/block), int4 edge loads, batched
// atomics for MLP. E must be a multiple of 8 (800000 is).
template <int K, int OUTF, int H>
__global__ __launch_bounds__(256) void gemm_scatter_k(
    const int* __restrict__ ei, int* __restrict__ cur,
    unsigned short* __restrict__ colE, int E, int GB,
    const float* __restrict__ in, const float* __restrict__ W,
    const float* __restrict__ a_src, const float* __restrict__ a_dst,
    unsigned short* __restrict__ hb, float* __restrict__ es,
    float* __restrict__ ed, int N)
{
    if (blockIdx.x >= GB) {
        int e0 = (blockIdx.x - GB) * 2048 + threadIdx.x * 8;
        if (e0 + 8 <= E) {
            int4 sa = *(const int4*)(ei + e0);
            int4 sb = *(const int4*)(ei + e0 + 4);
            int4 da = *(const int4*)(ei + E + e0);
            int4 db = *(const int4*)(ei + E + e0 + 4);
            int ss[8] = {sa.x, sa.y, sa.z, sa.w, sb.x, sb.y, sb.z, sb.w};
            int dd[8] = {da.x, da.y, da.z, da.w, db.x, db.y, db.z, db.w};
            int pos[8];
#pragma unroll
            for (int u = 0; u < 8; ++u)
                pos[u] = atomicAdd(&cur[dd[u]], 1) & 63;
#pragma unroll
            for (int u = 0; u < 8; ++u)
                colE[((size_t)dd[u] << 6) + pos[u]] = (unsigned short)ss[u];
        } else {
            int i = e0 - E;   // self-loop range (E % 8 == 0 -> no straddle)
            if (i >= 0) {
#pragma unroll
                for (int u = 0; u < 8; ++u) {
                    int d = i + u;
                    if (d < N) {
                        int pos = atomicAdd(&cur[d], 1) & 63;
                        colE[((size_t)d << 6) + pos] = (unsigned short)d;
                    }
                }
            }
        }
        return;
    }
    gemm_attn_body<K, OUTF, H, false>(blockIdx.x, in, W, nullptr, nullptr,
                                      a_src, a_dst, hb, es, ed, N);
}

// ---------------------------------------------------------------------------
// Fused softmax + gather + BN partial stats + LAST-BLOCK BN FINALIZE.
// ELL rows (ushort cols): base = node*64, deg = cur[node] clamped to 64.
// LPN = H*16 lanes/node. Last block (atomic counter) reduces the 128 psum
// slots, computes scale/shift, re-zeros partials (was bn_final_k).
// ---------------------------------------------------------------------------
template <int H>
__global__ __launch_bounds__(256) void node_sg_k(
    const int* __restrict__ degA, const unsigned short* __restrict__ colE,
    const float* __restrict__ es, const float* __restrict__ ed,
    const unsigned short* __restrict__ hb, float* __restrict__ out,
    float* __restrict__ psum, float* __restrict__ psumsq,
    const float* __restrict__ gamma, const float* __restrict__ beta,
    float* __restrict__ scale, float* __restrict__ shift,
    int* __restrict__ syncc, int nblocks, int N)
{
    constexpr int LPN = H * 16;            // 32 (H=2) or 16 (H=1)
    constexpr int F = LPN * 2;
    constexpr int NPB = 256 / LPN;
    int t = blockIdx.x * 256 + threadIdx.x;
    int node = t / LPN;
    int lane = t - node * LPN;
    const bool valid = node < N;

    const uint* h2 = (const uint*)hb;
    const float2* es2 = (const float2*)es;

    size_t base = (size_t)node << 6;
    int deg = 0;
    float ed0 = 0.f, ed1 = 0.f;
    if (valid) {
        deg = degA[node];
        if (deg > 64) deg = 64;
        if constexpr (H == 2) {
            float2 e = ((const float2*)ed)[node];
            ed0 = e.x; ed1 = e.y;
        } else {
            ed0 = ed[node];
        }
    }

    // ---- phase 1: cache first LPN edges; accumulate denominator ----
    int sc_ = 0;
    float x0 = 0.f, x1 = 0.f;
    if (lane < deg) {
        sc_ = colE[base + lane];
        if constexpr (H == 2) {
            float2 v = es2[sc_];
            x0 = __expf(lrelu(v.x + ed0));
            x1 = __expf(lrelu(v.y + ed1));
        } else {
            x0 = __expf(lrelu(es[sc_] + ed0));
        }
    }
    float s0 = x0, s1 = x1;
    for (int e = lane + LPN; e < deg; e += LPN) {
        int s = colE[base + e];
        if constexpr (H == 2) {
            float2 v = es2[s];
            s0 += __expf(lrelu(v.x + ed0));
            s1 += __expf(lrelu(v.y + ed1));
        } else {
            s0 += __expf(lrelu(es[s] + ed0));
        }
    }
#pragma unroll
    for (int m = LPN / 2; m; m >>= 1) {
        s0 += __shfl_xor(s0, m, LPN);
        if (H == 2) s1 += __shfl_xor(s1, m, LPN);
    }
    float rd0 = 1.f / (s0 + 1e-16f);
    float rd1 = (H == 2) ? 1.f / (s1 + 1e-16f) : 0.f;

    // ---- phase 2: weighted gather (broadcast src/exp via shfl) ----
    const bool hi = (H == 2) && (lane >= 16);
    float acc0 = 0.f, acc1 = 0.f;
    int dcap = deg < LPN ? deg : LPN;
    int e = 0;
    for (; e + 8 <= dcap; e += 8) {
        int sI[8];
        float a[8];
#pragma unroll
        for (int u = 0; u < 8; ++u) {
            sI[u] = __shfl(sc_, e + u, LPN);
            float a0 = __shfl(x0, e + u, LPN);
            if constexpr (H == 2) {
                float a1 = __shfl(x1, e + u, LPN);
                a[u] = hi ? a1 * rd1 : a0 * rd0;
            } else {
                a[u] = a0 * rd0;
            }
        }
        uint v[8];
#pragma unroll
        for (int u = 0; u < 8; ++u) v[u] = h2[(size_t)sI[u] * LPN + lane];
#pragma unroll
        for (int u = 0; u < 8; ++u) {
            acc0 += a[u] * bf2f((unsigned short)v[u]);
            acc1 += a[u] * bf2f((unsigned short)(v[u] >> 16));
        }
    }
    for (; e + 4 <= dcap; e += 4) {
        int sI[4];
        float a[4];
#pragma unroll
        for (int u = 0; u < 4; ++u) {
            sI[u] = __shfl(sc_, e + u, LPN);
            float a0 = __shfl(x0, e + u, LPN);
            if constexpr (H == 2) {
                float a1 = __shfl(x1, e + u, LPN);
                a[u] = hi ? a1 * rd1 : a0 * rd0;
            } else {
                a[u] = a0 * rd0;
            }
        }
        uint v[4];
#pragma unroll
        for (int u = 0; u < 4; ++u) v[u] = h2[(size_t)sI[u] * LPN + lane];
#pragma unroll
        for (int u = 0; u < 4; ++u) {
            acc0 += a[u] * bf2f((unsigned short)v[u]);
            acc1 += a[u] * bf2f((unsigned short)(v[u] >> 16));
        }
    }
    for (; e < dcap; ++e) {
        int sI = __shfl(sc_, e, LPN);
        float a0 = __shfl(x0, e, LPN);
        float a;
        if constexpr (H == 2) {
            float a1 = __shfl(x1, e, LPN);
            a = hi ? a1 * rd1 : a0 * rd0;
        } else {
            a = a0 * rd0;
        }
        uint v = h2[(size_t)sI * LPN + lane];
        acc0 += a * bf2f((unsigned short)v);
        acc1 += a * bf2f((unsigned short)(v >> 16));
    }
    for (int e2 = LPN; e2 < deg; ++e2) {       // rare tail (deg > LPN)
        int s = colE[base + e2];
        float a;
        if constexpr (H == 2) {
            float2 vv = es2[s];
            a = hi ? __expf(lrelu(vv.y + ed1)) * rd1
                   : __expf(lrelu(vv.x + ed0)) * rd0;
        } else {
            a = __expf(lrelu(es[s] + ed0)) * rd0;
        }
        uint v = h2[(size_t)s * LPN + lane];
        acc0 += a * bf2f((unsigned short)v);
        acc1 += a * bf2f((unsigned short)(v >> 16));
    }
    if (valid)
        ((float2*)out)[(size_t)node * LPN + lane] = make_float2(acc0, acc1);

    // ---- BN partial stats: block reduce, strided atomic slots ----
    __shared__ float ls0[256], ls1[256];
    ls0[threadIdx.x] = acc0;
    ls1[threadIdx.x] = acc1;
    __syncthreads();
    if (threadIdx.x < LPN) {
        int l = threadIdx.x;
        float t0 = 0.f, t0q = 0.f, t1 = 0.f, t1q = 0.f;
#pragma unroll
        for (int g = 0; g < NPB; ++g) {
            float v0 = ls0[g * LPN + l], v1 = ls1[g * LPN + l];
            t0 += v0; t0q += v0 * v0;
            t1 += v1; t1q += v1 * v1;
        }
        int slot = (blockIdx.x & 127) * F;
        atomicAdd(&psum[slot + 2 * l], t0);
        atomicAdd(&psum[slot + 2 * l + 1], t1);
        atomicAdd(&psumsq[slot + 2 * l], t0q);
        atomicAdd(&psumsq[slot + 2 * l + 1], t1q);
    }

    // ---- last-block BN finalize (was bn_final_k) ----
    __shared__ int lastFlag;
    if (threadIdx.x == 0) {
        __threadfence();
        lastFlag = (atomicAdd(syncc, 1) == nblocks - 1) ? 1 : 0;
    }
    __syncthreads();
    if (lastFlag) {
        __threadfence();                   // acquire all blocks' atomics
        int f = threadIdx.x % F;
        int r = threadIdx.x / F;
        constexpr int R = 256 / F;
        float s = 0.f, s2 = 0.f;
        for (int b = r; b < 128; b += R) {
            s += psum[b * F + f];
            s2 += psumsq[b * F + f];
            psum[b * F + f] = 0.f;
            psumsq[b * F + f] = 0.f;
        }
        __shared__ float l1[256], l2[256];
        l1[threadIdx.x] = s;
        l2[threadIdx.x] = s2;
        __syncthreads();
        if (r == 0) {
            for (int g = 1; g < R; ++g) { s += l1[g * F + f]; s2 += l2[g * F + f]; }
            float inv = 1.f / (float)N;
            float mu = s * inv;
            float var = fmaxf(s2 * inv - mu * mu, 0.f);
            float rs = rsqrtf(var + 1e-5f);
            float sc = rs * gamma[f];
            scale[f] = sc;
            shift[f] = beta[f] - mu * sc;
        }
    }
}

__global__ __launch_bounds__(256) void out_final_k(
    const float* __restrict__ x, const float* __restrict__ scale,
    const float* __restrict__ shift, float* __restrict__ out, int total)
{
    int i = blockIdx.x * 256 + threadIdx.x;
    if (i >= total) return;
    int f = i & 31;
    out[i] = fmaxf(x[i] * scale[f] + shift[f], 0.f);
}

// ---------------------------------------------------------------------------

extern "C" void kernel_launch(void* const* d_in, const int* in_sizes, int n_in,
                              void* d_out, int out_size, void* d_ws,
                              size_t ws_size, hipStream_t stream)
{
    const float* x   = (const float*)d_in[0];
    const float* W1  = (const float*)d_in[1];
    const float* as1 = (const float*)d_in[2];
    const float* ad1 = (const float*)d_in[3];
    const float* g1  = (const float*)d_in[5];
    const float* be1 = (const float*)d_in[6];
    const float* W2  = (const float*)d_in[7];
    const float* as2 = (const float*)d_in[8];
    const float* ad2 = (const float*)d_in[9];
    const float* g2  = (const float*)d_in[11];
    const float* be2 = (const float*)d_in[12];
    const float* W3  = (const float*)d_in[13];
    const float* as3 = (const float*)d_in[14];
    const float* ad3 = (const float*)d_in[15];
    const float* g3  = (const float*)d_in[17];
    const float* be3 = (const float*)d_in[18];
    const int*   ei  = (const int*)d_in[19];

    const int N  = in_sizes[0] / 128;   // 50000
    const int E  = in_sizes[19] / 2;    // 800000
    const int Et = E + N;

    // Workspace layout (4-byte words). PS/PS2/cur/sync contiguous -> one memset.
    float* ws = (float*)d_ws;
    size_t off = 0;
    unsigned short* Hb = (unsigned short*)(ws + off); off += (size_t)N * 32; // bf16 [N,64]
    float* AGG = ws + off;  off += (size_t)N * 64;
    float* ES  = ws + off;  off += (size_t)N * 2;
    float* ED  = ws + off;  off += (size_t)N * 2;
    float* SC  = ws + off;  off += 64;
    float* SH  = ws + off;  off += 64;
    size_t zOff = off;
    float* PS  = ws + off;  off += (size_t)128 * 64;  // BN partials
    float* PS2 = ws + off;  off += (size_t)128 * 64;
    int* cur   = (int*)(ws + off);  off += N;         // ELL cursor -> deg
    int* syncA = (int*)(ws + off);  off += 4;         // last-block counters
    size_t zEnd = off;
    unsigned short* colE = (unsigned short*)(ws + off); off += (size_t)N * 32; // ushort[N*64]

    const int tiles      = (N + 127) / 128;
    const int gemm2Blocks = tiles * 2;   // head-split for OUTF=64
    const int gemm1Blocks = tiles;       // OUTF=32
    const int sg64Blocks = (int)(((size_t)N * 32 + 255) / 256);  // LPN=32
    const int sg32Blocks = (int)(((size_t)N * 16 + 255) / 256);  // LPN=16
    const int edgeBlocks = (Et + 2047) / 2048;   // 8 edges/thread
    const int n32Blocks  = (N * 32 + 255) / 256;

    // ---------------- init + (Layer-1 GEMM || ELL scatter) ----------------
    hipMemsetAsync(ws + zOff, 0, (zEnd - zOff) * sizeof(float), stream);
    gemm_scatter_k<128, 64, 2><<<gemm2Blocks + edgeBlocks, 256, 0, stream>>>(
        ei, cur, colE, E, gemm2Blocks,
        x, W1, as1, ad1, Hb, ES, ED, N);

    // ---------------- Layer 1 rest (BN finalize fused in last block) ------
    node_sg_k<2><<<sg64Blocks, 256, 0, stream>>>(
        cur, colE, ES, ED, Hb, AGG, PS, PS2, g1, be1, SC, SH,
        syncA + 0, sg64Blocks, N);

    // ---------------- Layer 2: 64 -> [2 x 32] ----------------
    gemm_attn_k<64, 64, 2, true><<<gemm2Blocks, 256, 0, stream>>>(
        AGG, W2, SC, SH, as2, ad2, Hb, ES, ED, N);
    node_sg_k<2><<<sg64Blocks, 256, 0, stream>>>(
        cur, colE, ES, ED, Hb, AGG, PS, PS2, g2, be2, SC, SH,
        syncA + 1, sg64Blocks, N);

    // ---------------- Layer 3: 64 -> [1 x 32] ----------------
    gemm_attn_k<64, 32, 1, true><<<gemm1Blocks, 256, 0, stream>>>(
        AGG, W3, SC, SH, as3, ad3, Hb, ES, ED, N);
    node_sg_k<1><<<sg32Blocks, 256, 0, stream>>>(
        cur, colE, ES, ED, Hb, AGG, PS, PS2, g3, be3, SC, SH,
        syncA + 2, sg32Blocks, N);
    out_final_k<<<n32Blocks, 256, 0, stream>>>(AGG, SC, SH, (float*)d_out, N * 32);
}

// Round 10
// 287.192 us; speedup vs baseline: 2.4448x; 2.4448x over previous
//
#include <hip/hip_runtime.h>

// ---------------------------------------------------------------------------
// GAT_L3: 3x (GATConv -> BatchNorm -> ReLU), N=50000, E=800000 (+N self-loops).
// r25 POST-MORTEM: last-block BN fusion poisoned node_sg (55 -> 213us/dispatch;
// threadfence/grid-protocol forced conservative coherence -> gather cache
// locality destroyed, FETCH 35MB on a 6.4MB cache-resident Hb). Reverted:
// bn_final_k is a separate 1-block kernel again. Lesson: never mix grid-sync
// protocols into cache-latency-critical kernels.
// Round 26: r23/r6 base + node_sg first-batch gather prefetch: issue the
// first 8 h2 loads (addresses known from sc_) BEFORE the softmax shfl-reduce;
// consume after. vmcnt/lgkmcnt independent -> gather latency hides behind
// reduce+exp. +16 VGPR (28->~45, same <=64 occupancy bucket).
// Round 27 (this): resubmit of r26 unchanged — broker/container failure gave
// no counters. Prediction stands: node_sg 55 -> 48-52us, total ~280-288us.
// ---------------------------------------------------------------------------

__device__ __forceinline__ float lrelu(float x) { return x > 0.f ? x : 0.2f * x; }
__device__ __forceinline__ unsigned short f2bf(float x) {
    unsigned u = __float_as_uint(x);
    return (unsigned short)((u + 0x7FFFu + ((u >> 16) & 1u)) >> 16);
}
__device__ __forceinline__ float bf2f(unsigned short v) {
    return __uint_as_float(((unsigned)v) << 16);
}

// ---------------------------------------------------------------------------
// Tiled GEMM + attention epilogue body (head-split, depth-1 register
// prefetch, unroll-1 K-loop; VGPR ~104, 4 waves/SIMD).
// ---------------------------------------------------------------------------
template <int K, int OUTF, int H, bool FUSE>
__device__ __forceinline__ void gemm_attn_body(
    int vbid, const float* __restrict__ in, const float* __restrict__ W,
    const float* __restrict__ scale, const float* __restrict__ shift,
    const float* __restrict__ a_src, const float* __restrict__ a_dst,
    unsigned short* __restrict__ hb, float* __restrict__ es,
    float* __restrict__ ed, int N)
{
    constexpr int BK = 32;
    constexpr int M = 128;
    constexpr int XS = BK + 4;
    constexpr int HS = OUTF / 32;
    constexpr int NC = K / BK;            // K-tiles: 4 (K=128) or 2 (K=64)
    __shared__ float xs[M * XS];
    __shared__ float wsl[32 * XS];
    __shared__ float redS[8 * 132];
    __shared__ float redD[8 * 132];

    const int tid = threadIdx.x;
    const int tile = (HS == 2) ? (vbid >> 1) : vbid;
    const int hs = (HS == 2) ? (vbid & 1) : 0;
    const int n0 = tile * M;
    const int jb = hs * 32;

    const int lane = tid & 31;
    const int jt = (tid >> 5) * 4;
    const int kq4 = (tid & 7) * 4;        // x-stage k-subcolumn
    const int nrow = tid >> 3;            // x-stage base row (i adds 32)
    const int wj = tid & 31;              // W-stage col
    const int wk = tid >> 5;              // W-stage base k (i adds 8)

    float acc[4][4];
#pragma unroll
    for (int i = 0; i < 4; ++i)
#pragma unroll
        for (int jj = 0; jj < 4; ++jj) acc[i][jj] = 0.f;

    // depth-1 register prefetch buffers
    float4 xr[4];
    float wr[4];

    // prologue: K-tile 0 -> regs
#pragma unroll
    for (int i = 0; i < 4; ++i) {
        int gn = n0 + nrow + 32 * i;
        if (gn >= N) gn = N - 1;
        xr[i] = *(const float4*)(in + (size_t)gn * K + kq4);
    }
#pragma unroll
    for (int i = 0; i < 4; ++i)
        wr[i] = W[(size_t)(wk + 8 * i) * OUTF + jb + wj];

#pragma unroll 1
    for (int c = 0; c < NC; ++c) {
        const int kc = c * BK;
        float4 sc, sh;
        if constexpr (FUSE) {            // column kq4 fixed for this thread
            sc = *(const float4*)(scale + kc + kq4);
            sh = *(const float4*)(shift + kc + kq4);
        }
        __syncthreads();   // previous compute done; LDS safe to overwrite
        // regs -> LDS (BN+ReLU applied here on the FUSE path)
#pragma unroll
        for (int i = 0; i < 4; ++i) {
            float4 v = xr[i];
            if constexpr (FUSE) {
                v.x = fmaxf(v.x * sc.x + sh.x, 0.f);
                v.y = fmaxf(v.y * sc.y + sh.y, 0.f);
                v.z = fmaxf(v.z * sc.z + sh.z, 0.f);
                v.w = fmaxf(v.w * sc.w + sh.w, 0.f);
            }
            *(float4*)&xs[(nrow + 32 * i) * XS + kq4] = v;
        }
#pragma unroll
        for (int i = 0; i < 4; ++i)
            wsl[wj * XS + wk + 8 * i] = wr[i];
        __syncthreads();   // staged tile visible
        // prefetch NEXT K-tile into regs; loads fly during compute below
        if (c + 1 < NC) {
            const int kn = kc + BK;
#pragma unroll
            for (int i = 0; i < 4; ++i) {
                int gn = n0 + nrow + 32 * i;
                if (gn >= N) gn = N - 1;
                xr[i] = *(const float4*)(in + (size_t)gn * K + kn + kq4);
            }
#pragma unroll
            for (int i = 0; i < 4; ++i)
                wr[i] = W[(size_t)(kn + wk + 8 * i) * OUTF + jb + wj];
        }
        // compute on staged tile
#pragma unroll
        for (int k4 = 0; k4 < BK; k4 += 4) {
            float4 xv[4];
#pragma unroll
            for (int i = 0; i < 4; ++i)
                xv[i] = *(float4*)&xs[(lane + 32 * i) * XS + k4];
#pragma unroll
            for (int jj = 0; jj < 4; ++jj) {
                float4 wv = *(float4*)&wsl[(jt + jj) * XS + k4];
#pragma unroll
                for (int i = 0; i < 4; ++i)
                    acc[i][jj] += xv[i].x * wv.x + xv[i].y * wv.y
                                + xv[i].z * wv.z + xv[i].w * wv.w;
            }
        }
    }

    const int jg = tid >> 5;
#pragma unroll
    for (int i = 0; i < 4; ++i) {
        int r = lane + 32 * i;
        int gn = n0 + r;
        float p = 0.f, q = 0.f;
#pragma unroll
        for (int jj = 0; jj < 4; ++jj) {
            p += acc[i][jj] * a_src[jb + jt + jj];
            q += acc[i][jj] * a_dst[jb + jt + jj];
        }
        if (gn < N) {
            uint2 u;
            u.x = (unsigned)f2bf(acc[i][0]) | ((unsigned)f2bf(acc[i][1]) << 16);
            u.y = (unsigned)f2bf(acc[i][2]) | ((unsigned)f2bf(acc[i][3]) << 16);
            *(uint2*)(hb + (size_t)gn * OUTF + jb + jt) = u;
        }
        redS[jg * 132 + r] = p;
        redD[jg * 132 + r] = q;
    }
    __syncthreads();
    if (tid < M) {
        int gn = n0 + tid;
        if (gn < N) {
            float e = 0.f, d = 0.f;
#pragma unroll
            for (int g = 0; g < 8; ++g) {
                e += redS[g * 132 + tid];
                d += redD[g * 132 + tid];
            }
            es[gn * H + hs] = e;
            ed[gn * H + hs] = d;
        }
    }
}

template <int K, int OUTF, int H, bool FUSE>
__global__ __launch_bounds__(256) void gemm_attn_k(
    const float* __restrict__ in, const float* __restrict__ W,
    const float* __restrict__ scale, const float* __restrict__ shift,
    const float* __restrict__ a_src, const float* __restrict__ a_dst,
    unsigned short* __restrict__ hb, float* __restrict__ es,
    float* __restrict__ ed, int N)
{
    gemm_attn_body<K, OUTF, H, FUSE>(blockIdx.x, in, W, scale, shift,
                                     a_src, a_dst, hb, es, ed, N);
}

// Fused: first GB blocks run layer-1 gemm (seed every CU); rest do the ELL
// scatter. Scatter: 8 edges/thread (2048/block), int4 edge loads, batched
// atomics for MLP. E must be a multiple of 8 (800000 is).
template <int K, int OUTF, int H>
__global__ __launch_bounds__(256) void gemm_scatter_k(
    const int* __restrict__ ei, int* __restrict__ cur,
    unsigned short* __restrict__ colE, int E, int GB,
    const float* __restrict__ in, const float* __restrict__ W,
    const float* __restrict__ a_src, const float* __restrict__ a_dst,
    unsigned short* __restrict__ hb, float* __restrict__ es,
    float* __restrict__ ed, int N)
{
    if (blockIdx.x >= GB) {
        int e0 = (blockIdx.x - GB) * 2048 + threadIdx.x * 8;
        if (e0 + 8 <= E) {
            int4 sa = *(const int4*)(ei + e0);
            int4 sb = *(const int4*)(ei + e0 + 4);
            int4 da = *(const int4*)(ei + E + e0);
            int4 db = *(const int4*)(ei + E + e0 + 4);
            int ss[8] = {sa.x, sa.y, sa.z, sa.w, sb.x, sb.y, sb.z, sb.w};
            int dd[8] = {da.x, da.y, da.z, da.w, db.x, db.y, db.z, db.w};
            int pos[8];
#pragma unroll
            for (int u = 0; u < 8; ++u)
                pos[u] = atomicAdd(&cur[dd[u]], 1) & 63;
#pragma unroll
            for (int u = 0; u < 8; ++u)
                colE[((size_t)dd[u] << 6) + pos[u]] = (unsigned short)ss[u];
        } else {
            int i = e0 - E;   // self-loop range (E % 8 == 0 -> no straddle)
            if (i >= 0) {
#pragma unroll
                for (int u = 0; u < 8; ++u) {
                    int d = i + u;
                    if (d < N) {
                        int pos = atomicAdd(&cur[d], 1) & 63;
                        colE[((size_t)d << 6) + pos] = (unsigned short)d;
                    }
                }
            }
        }
        return;
    }
    gemm_attn_body<K, OUTF, H, false>(blockIdx.x, in, W, nullptr, nullptr,
                                      a_src, a_dst, hb, es, ed, N);
}

// ---------------------------------------------------------------------------
// Fused softmax + gather + BN partial stats. ELL rows (ushort cols):
// base = node*64, deg = cur[node] clamped to 64. LPN = H*16 lanes/node.
// First gather batch prefetched before the softmax reduce (vmcnt overlaps
// lgkmcnt shfl chain).
// ---------------------------------------------------------------------------
template <int H>
__global__ __launch_bounds__(256) void node_sg_k(
    const int* __restrict__ degA, const unsigned short* __restrict__ colE,
    const float* __restrict__ es, const float* __restrict__ ed,
    const unsigned short* __restrict__ hb, float* __restrict__ out,
    float* __restrict__ psum, float* __restrict__ psumsq, int N)
{
    constexpr int LPN = H * 16;            // 32 (H=2) or 16 (H=1)
    constexpr int F = LPN * 2;
    constexpr int NPB = 256 / LPN;
    int t = blockIdx.x * 256 + threadIdx.x;
    int node = t / LPN;
    int lane = t - node * LPN;
    const bool valid = node < N;

    const uint* h2 = (const uint*)hb;
    const float2* es2 = (const float2*)es;

    size_t base = (size_t)node << 6;
    int deg = 0;
    float ed0 = 0.f, ed1 = 0.f;
    if (valid) {
        deg = degA[node];
        if (deg > 64) deg = 64;
        if constexpr (H == 2) {
            float2 e = ((const float2*)ed)[node];
            ed0 = e.x; ed1 = e.y;
        } else {
            ed0 = ed[node];
        }
    }

    // ---- phase 1: cache first LPN edges; accumulate denominator ----
    int sc_ = 0;
    float x0 = 0.f, x1 = 0.f;
    if (lane < deg) {
        sc_ = colE[base + lane];
        if constexpr (H == 2) {
            float2 v = es2[sc_];
            x0 = __expf(lrelu(v.x + ed0));
            x1 = __expf(lrelu(v.y + ed1));
        } else {
            x0 = __expf(lrelu(es[sc_] + ed0));
        }
    }
    float s0 = x0, s1 = x1;
    for (int e = lane + LPN; e < deg; e += LPN) {
        int s = colE[base + e];
        if constexpr (H == 2) {
            float2 v = es2[s];
            s0 += __expf(lrelu(v.x + ed0));
            s1 += __expf(lrelu(v.y + ed1));
        } else {
            s0 += __expf(lrelu(es[s] + ed0));
        }
    }

    // ---- prefetch first gather batch: addresses need only sc_ ----
    const int dcap = deg < LPN ? deg : LPN;
    const bool pre = (dcap >= 8);
    int sI0[8];
    uint v0[8];
    if (pre) {
#pragma unroll
        for (int u = 0; u < 8; ++u) sI0[u] = __shfl(sc_, u, LPN);
#pragma unroll
        for (int u = 0; u < 8; ++u) v0[u] = h2[(size_t)sI0[u] * LPN + lane];
    }

    // ---- softmax reduce (shfl chain overlaps the loads above) ----
#pragma unroll
    for (int m = LPN / 2; m; m >>= 1) {
        s0 += __shfl_xor(s0, m, LPN);
        if (H == 2) s1 += __shfl_xor(s1, m, LPN);
    }
    float rd0 = 1.f / (s0 + 1e-16f);
    float rd1 = (H == 2) ? 1.f / (s1 + 1e-16f) : 0.f;

    // ---- phase 2: weighted gather (broadcast src/exp via shfl) ----
    const bool hi = (H == 2) && (lane >= 16);
    float acc0 = 0.f, acc1 = 0.f;
    int e = 0;
    if (pre) {
        float a[8];
#pragma unroll
        for (int u = 0; u < 8; ++u) {
            float a0 = __shfl(x0, u, LPN);
            if constexpr (H == 2) {
                float a1 = __shfl(x1, u, LPN);
                a[u] = hi ? a1 * rd1 : a0 * rd0;
            } else {
                a[u] = a0 * rd0;
            }
        }
#pragma unroll
        for (int u = 0; u < 8; ++u) {
            acc0 += a[u] * bf2f((unsigned short)v0[u]);
            acc1 += a[u] * bf2f((unsigned short)(v0[u] >> 16));
        }
        e = 8;
    }
    for (; e + 8 <= dcap; e += 8) {
        int sI[8];
        float a[8];
#pragma unroll
        for (int u = 0; u < 8; ++u) {
            sI[u] = __shfl(sc_, e + u, LPN);
            float a0 = __shfl(x0, e + u, LPN);
            if constexpr (H == 2) {
                float a1 = __shfl(x1, e + u, LPN);
                a[u] = hi ? a1 * rd1 : a0 * rd0;
            } else {
                a[u] = a0 * rd0;
            }
        }
        uint v[8];
#pragma unroll
        for (int u = 0; u < 8; ++u) v[u] = h2[(size_t)sI[u] * LPN + lane];
#pragma unroll
        for (int u = 0; u < 8; ++u) {
            acc0 += a[u] * bf2f((unsigned short)v[u]);
            acc1 += a[u] * bf2f((unsigned short)(v[u] >> 16));
        }
    }
    for (; e + 4 <= dcap; e += 4) {
        int sI[4];
        float a[4];
#pragma unroll
        for (int u = 0; u < 4; ++u) {
            sI[u] = __shfl(sc_, e + u, LPN);
            float a0 = __shfl(x0, e + u, LPN);
            if constexpr (H == 2) {
                float a1 = __shfl(x1, e + u, LPN);
                a[u] = hi ? a1 * rd1 : a0 * rd0;
            } else {
                a[u] = a0 * rd0;
            }
        }
        uint v[4];
#pragma unroll
        for (int u = 0; u < 4; ++u) v[u] = h2[(size_t)sI[u] * LPN + lane];
#pragma unroll
        for (int u = 0; u < 4; ++u) {
            acc0 += a[u] * bf2f((unsigned short)v[u]);
            acc1 += a[u] * bf2f((unsigned short)(v[u] >> 16));
        }
    }
    for (; e < dcap; ++e) {
        int sI = __shfl(sc_, e, LPN);
        float a0 = __shfl(x0, e, LPN);
        float a;
        if constexpr (H == 2) {
            float a1 = __shfl(x1, e, LPN);
            a = hi ? a1 * rd1 : a0 * rd0;
        } else {
            a = a0 * rd0;
        }
        uint v = h2[(size_t)sI * LPN + lane];
        acc0 += a * bf2f((unsigned short)v);
        acc1 += a * bf2f((unsigned short)(v >> 16));
    }
    for (int e2 = LPN; e2 < deg; ++e2) {       // rare tail (deg > LPN)
        int s = colE[base + e2];
        float a;
        if constexpr (H == 2) {
            float2 vv = es2[s];
            a = hi ? __expf(lrelu(vv.y + ed1)) * rd1
                   : __expf(lrelu(vv.x + ed0)) * rd0;
        } else {
            a = __expf(lrelu(es[s] + ed0)) * rd0;
        }
        uint v = h2[(size_t)s * LPN + lane];
        acc0 += a * bf2f((unsigned short)v);
        acc1 += a * bf2f((unsigned short)(v >> 16));
    }
    if (valid)
        ((float2*)out)[(size_t)node * LPN + lane] = make_float2(acc0, acc1);

    // ---- BN partial stats: block reduce, strided atomic slots ----
    __shared__ float ls0[256], ls1[256];
    ls0[threadIdx.x] = acc0;
    ls1[threadIdx.x] = acc1;
    __syncthreads();
    if (threadIdx.x < LPN) {
        int l = threadIdx.x;
        float t0 = 0.f, t0q = 0.f, t1 = 0.f, t1q = 0.f;
#pragma unroll
        for (int g = 0; g < NPB; ++g) {
            float v0_ = ls0[g * LPN + l], v1_ = ls1[g * LPN + l];
            t0 += v0_; t0q += v0_ * v0_;
            t1 += v1_; t1q += v1_ * v1_;
        }
        int slot = (blockIdx.x & 127) * F;
        atomicAdd(&psum[slot + 2 * l], t0);
        atomicAdd(&psum[slot + 2 * l + 1], t1);
        atomicAdd(&psumsq[slot + 2 * l], t0q);
        atomicAdd(&psumsq[slot + 2 * l + 1], t1q);
    }
}

// ---------------------------------------------------------------------------
// BN finalize: 256 threads = F x (256/F); LDS reduce; re-zeros partials.
// ---------------------------------------------------------------------------
__global__ void bn_final_k(float* __restrict__ psum,
                           float* __restrict__ psumsq,
                           const float* __restrict__ gamma,
                           const float* __restrict__ beta,
                           float* __restrict__ scale, float* __restrict__ shift,
                           int N, int F)
{
    int f = threadIdx.x % F;
    int r = threadIdx.x / F;
    int R = 256 / F;
    float s = 0.f, s2 = 0.f;
    for (int b = r; b < 128; b += R) {
        s += psum[b * F + f];
        s2 += psumsq[b * F + f];
        psum[b * F + f] = 0.f;
        psumsq[b * F + f] = 0.f;
    }
    __shared__ float l1[256], l2[256];
    l1[threadIdx.x] = s;
    l2[threadIdx.x] = s2;
    __syncthreads();
    if (r == 0) {
        for (int g = 1; g < R; ++g) { s += l1[g * F + f]; s2 += l2[g * F + f]; }
        float inv = 1.f / (float)N;
        float mu = s * inv;
        float var = s2 * inv - mu * mu;
        var = fmaxf(var, 0.f);
        float rs = rsqrtf(var + 1e-5f);
        float sc = rs * gamma[f];
        scale[f] = sc;
        shift[f] = beta[f] - mu * sc;
    }
}

__global__ __launch_bounds__(256) void out_final_k(
    const float* __restrict__ x, const float* __restrict__ scale,
    const float* __restrict__ shift, float* __restrict__ out, int total)
{
    int i = blockIdx.x * 256 + threadIdx.x;
    if (i >= total) return;
    int f = i & 31;
    out[i] = fmaxf(x[i] * scale[f] + shift[f], 0.f);
}

// ---------------------------------------------------------------------------

extern "C" void kernel_launch(void* const* d_in, const int* in_sizes, int n_in,
                              void* d_out, int out_size, void* d_ws,
                              size_t ws_size, hipStream_t stream)
{
    const float* x   = (const float*)d_in[0];
    const float* W1  = (const float*)d_in[1];
    const float* as1 = (const float*)d_in[2];
    const float* ad1 = (const float*)d_in[3];
    const float* g1  = (const float*)d_in[5];
    const float* be1 = (const float*)d_in[6];
    const float* W2  = (const float*)d_in[7];
    const float* as2 = (const float*)d_in[8];
    const float* ad2 = (const float*)d_in[9];
    const float* g2  = (const float*)d_in[11];
    const float* be2 = (const float*)d_in[12];
    const float* W3  = (const float*)d_in[13];
    const float* as3 = (const float*)d_in[14];
    const float* ad3 = (const float*)d_in[15];
    const float* g3  = (const float*)d_in[17];
    const float* be3 = (const float*)d_in[18];
    const int*   ei  = (const int*)d_in[19];

    const int N  = in_sizes[0] / 128;   // 50000
    const int E  = in_sizes[19] / 2;    // 800000
    const int Et = E + N;

    // Workspace layout (4-byte words). PS/PS2/cur contiguous -> one memset.
    float* ws = (float*)d_ws;
    size_t off = 0;
    unsigned short* Hb = (unsigned short*)(ws + off); off += (size_t)N * 32; // bf16 [N,64]
    float* AGG = ws + off;  off += (size_t)N * 64;
    float* ES  = ws + off;  off += (size_t)N * 2;
    float* ED  = ws + off;  off += (size_t)N * 2;
    float* SC  = ws + off;  off += 64;
    float* SH  = ws + off;  off += 64;
    size_t zOff = off;
    float* PS  = ws + off;  off += (size_t)128 * 64;  // BN partials
    float* PS2 = ws + off;  off += (size_t)128 * 64;
    int* cur   = (int*)(ws + off);  off += N;         // ELL cursor -> deg
    size_t zEnd = off;
    unsigned short* colE = (unsigned short*)(ws + off); off += (size_t)N * 32; // ushort[N*64]

    const int tiles      = (N + 127) / 128;
    const int gemm2Blocks = tiles * 2;   // head-split for OUTF=64
    const int gemm1Blocks = tiles;       // OUTF=32
    const int sg64Blocks = (int)(((size_t)N * 32 + 255) / 256);  // LPN=32
    const int sg32Blocks = (int)(((size_t)N * 16 + 255) / 256);  // LPN=16
    const int edgeBlocks = (Et + 2047) / 2048;   // 8 edges/thread
    const int n32Blocks  = (N * 32 + 255) / 256;

    // ---------------- init + (Layer-1 GEMM || ELL scatter) ----------------
    hipMemsetAsync(ws + zOff, 0, (zEnd - zOff) * sizeof(float), stream);
    gemm_scatter_k<128, 64, 2><<<gemm2Blocks + edgeBlocks, 256, 0, stream>>>(
        ei, cur, colE, E, gemm2Blocks,
        x, W1, as1, ad1, Hb, ES, ED, N);

    // ---------------- Layer 1 rest ----------------
    node_sg_k<2><<<sg64Blocks, 256, 0, stream>>>(cur, colE, ES, ED, Hb, AGG, PS, PS2, N);
    bn_final_k<<<1, 256, 0, stream>>>(PS, PS2, g1, be1, SC, SH, N, 64);

    // ---------------- Layer 2: 64 -> [2 x 32] ----------------
    gemm_attn_k<64, 64, 2, true><<<gemm2Blocks, 256, 0, stream>>>(
        AGG, W2, SC, SH, as2, ad2, Hb, ES, ED, N);
    node_sg_k<2><<<sg64Blocks, 256, 0, stream>>>(cur, colE, ES, ED, Hb, AGG, PS, PS2, N);
    bn_final_k<<<1, 256, 0, stream>>>(PS, PS2, g2, be2, SC, SH, N, 64);

    // ---------------- Layer 3: 64 -> [1 x 32] ----------------
    gemm_attn_k<64, 32, 1, true><<<gemm1Blocks, 256, 0, stream>>>(
        AGG, W3, SC, SH, as3, ad3, Hb, ES, ED, N);
    node_sg_k<1><<<sg32Blocks, 256, 0, stream>>>(cur, colE, ES, ED, Hb, AGG, PS, PS2, N);
    bn_final_k<<<1, 256, 0, stream>>>(PS, PS2, g3, be3, SC, SH, N, 32);
    out_final_k<<<n32Blocks, 256, 0, stream>>>(AGG, SC, SH, (float*)d_out, N * 32);
}

// Round 11
// 285.374 us; speedup vs baseline: 2.4603x; 1.0064x over previous
//
#include <hip/hip_runtime.h>

// ---------------------------------------------------------------------------
// GAT_L3: 3x (GATConv -> BatchNorm -> ReLU), N=50000, E=800000 (+N self-loops).
// r26/r27: node_sg first-batch gather prefetch -> 293 -> 287.2us. Committed.
// Round 28 (this): GEMM occupancy attack. rocprof: fused 62us, VALU 16% /
// HBM 18% / occ 14.7% -> wave-slot starved (VGPR 104 = 4 waves/SIMD bucket;
// after scatter retires only ~3 GEMM blocks/CU remain). Change: M=128 -> 64
// tiles (acc[2][4], 2-float4 x-stage) + DROP the depth-1 prefetch (measured
// wash r3-vs-r6) -> target VGPR <= 64 = 8 waves/SIMD. 2x blocks (1564) also
// shortens the drain tail; LDS 18KB -> 9 blocks/CU.
// Predict: VGPR <= 64 -> occ ~28%, fused 62 -> 42-48us, total ~255-270us.
// If VGPR 65-80: only balance gain, fused ~55-58 -> that kills this line.
// ---------------------------------------------------------------------------

__device__ __forceinline__ float lrelu(float x) { return x > 0.f ? x : 0.2f * x; }
__device__ __forceinline__ unsigned short f2bf(float x) {
    unsigned u = __float_as_uint(x);
    return (unsigned short)((u + 0x7FFFu + ((u >> 16) & 1u)) >> 16);
}
__device__ __forceinline__ float bf2f(unsigned short v) {
    return __uint_as_float(((unsigned)v) << 16);
}

// ---------------------------------------------------------------------------
// Tiled GEMM + attention epilogue body. M=64 rows/block, head-split on OUTF.
// 256 threads = 8 col-groups x 32 lanes; thread owns 2 rows x 4 cols.
// No register prefetch (keeps VGPR minimal; pipeline was measured a wash).
// ---------------------------------------------------------------------------
template <int K, int OUTF, int H, bool FUSE>
__device__ __forceinline__ void gemm_attn_body(
    int vbid, const float* __restrict__ in, const float* __restrict__ W,
    const float* __restrict__ scale, const float* __restrict__ shift,
    const float* __restrict__ a_src, const float* __restrict__ a_dst,
    unsigned short* __restrict__ hb, float* __restrict__ es,
    float* __restrict__ ed, int N)
{
    constexpr int BK = 32;
    constexpr int M = 64;
    constexpr int XS = BK + 4;
    constexpr int HS = OUTF / 32;
    constexpr int NC = K / BK;            // K-tiles: 4 (K=128) or 2 (K=64)
    __shared__ float xs[M * XS];          // 9216 B
    __shared__ float wsl[32 * XS];        // 4608 B
    __shared__ float redS[8 * 68];        // 2176 B
    __shared__ float redD[8 * 68];        // 2176 B

    const int tid = threadIdx.x;
    const int tile = (HS == 2) ? (vbid >> 1) : vbid;
    const int hs = (HS == 2) ? (vbid & 1) : 0;
    const int n0 = tile * M;
    const int jb = hs * 32;

    const int lane = tid & 31;
    const int jt = (tid >> 5) * 4;
    const int kq8 = (tid & 3) * 8;        // x-stage k-subcolumn (8 floats)
    const int nrow = tid >> 2;            // x-stage row (0..63)
    const int wj = tid & 31;              // W-stage col
    const int wk = tid >> 5;              // W-stage base k (i adds 8)

    float acc[2][4];
#pragma unroll
    for (int i = 0; i < 2; ++i)
#pragma unroll
        for (int jj = 0; jj < 4; ++jj) acc[i][jj] = 0.f;

    int gx = n0 + nrow;
    if (gx >= N) gx = N - 1;
    const float* xrow = in + (size_t)gx * K;

#pragma unroll 1
    for (int c = 0; c < NC; ++c) {
        const int kc = c * BK;
        // load this K-tile's x-slice (2 float4) + W-slice (4 scalars)
        float4 v0 = *(const float4*)(xrow + kc + kq8);
        float4 v1 = *(const float4*)(xrow + kc + kq8 + 4);
        if constexpr (FUSE) {
            float4 sc0 = *(const float4*)(scale + kc + kq8);
            float4 sh0 = *(const float4*)(shift + kc + kq8);
            float4 sc1 = *(const float4*)(scale + kc + kq8 + 4);
            float4 sh1 = *(const float4*)(shift + kc + kq8 + 4);
            v0.x = fmaxf(v0.x * sc0.x + sh0.x, 0.f);
            v0.y = fmaxf(v0.y * sc0.y + sh0.y, 0.f);
            v0.z = fmaxf(v0.z * sc0.z + sh0.z, 0.f);
            v0.w = fmaxf(v0.w * sc0.w + sh0.w, 0.f);
            v1.x = fmaxf(v1.x * sc1.x + sh1.x, 0.f);
            v1.y = fmaxf(v1.y * sc1.y + sh1.y, 0.f);
            v1.z = fmaxf(v1.z * sc1.z + sh1.z, 0.f);
            v1.w = fmaxf(v1.w * sc1.w + sh1.w, 0.f);
        }
        float w0 = W[(size_t)(kc + wk) * OUTF + jb + wj];
        float w1 = W[(size_t)(kc + wk + 8) * OUTF + jb + wj];
        float w2 = W[(size_t)(kc + wk + 16) * OUTF + jb + wj];
        float w3 = W[(size_t)(kc + wk + 24) * OUTF + jb + wj];

        __syncthreads();   // previous compute done; LDS safe to overwrite
        *(float4*)&xs[nrow * XS + kq8] = v0;
        *(float4*)&xs[nrow * XS + kq8 + 4] = v1;
        wsl[wj * XS + wk] = w0;
        wsl[wj * XS + wk + 8] = w1;
        wsl[wj * XS + wk + 16] = w2;
        wsl[wj * XS + wk + 24] = w3;
        __syncthreads();   // staged tile visible

        // compute on staged tile
#pragma unroll
        for (int k4 = 0; k4 < BK; k4 += 4) {
            float4 xv[2];
#pragma unroll
            for (int i = 0; i < 2; ++i)
                xv[i] = *(float4*)&xs[(lane + 32 * i) * XS + k4];
#pragma unroll
            for (int jj = 0; jj < 4; ++jj) {
                float4 wv = *(float4*)&wsl[(jt + jj) * XS + k4];
#pragma unroll
                for (int i = 0; i < 2; ++i)
                    acc[i][jj] += xv[i].x * wv.x + xv[i].y * wv.y
                                + xv[i].z * wv.z + xv[i].w * wv.w;
            }
        }
    }

    const int jg = tid >> 5;
#pragma unroll
    for (int i = 0; i < 2; ++i) {
        int r = lane + 32 * i;
        int gn = n0 + r;
        float p = 0.f, q = 0.f;
#pragma unroll
        for (int jj = 0; jj < 4; ++jj) {
            p += acc[i][jj] * a_src[jb + jt + jj];
            q += acc[i][jj] * a_dst[jb + jt + jj];
        }
        if (gn < N) {
            uint2 u;
            u.x = (unsigned)f2bf(acc[i][0]) | ((unsigned)f2bf(acc[i][1]) << 16);
            u.y = (unsigned)f2bf(acc[i][2]) | ((unsigned)f2bf(acc[i][3]) << 16);
            *(uint2*)(hb + (size_t)gn * OUTF + jb + jt) = u;
        }
        redS[jg * 68 + r] = p;
        redD[jg * 68 + r] = q;
    }
    __syncthreads();
    if (tid < M) {
        int gn = n0 + tid;
        if (gn < N) {
            float e = 0.f, d = 0.f;
#pragma unroll
            for (int g = 0; g < 8; ++g) {
                e += redS[g * 68 + tid];
                d += redD[g * 68 + tid];
            }
            es[gn * H + hs] = e;
            ed[gn * H + hs] = d;
        }
    }
}

template <int K, int OUTF, int H, bool FUSE>
__global__ __launch_bounds__(256) void gemm_attn_k(
    const float* __restrict__ in, const float* __restrict__ W,
    const float* __restrict__ scale, const float* __restrict__ shift,
    const float* __restrict__ a_src, const float* __restrict__ a_dst,
    unsigned short* __restrict__ hb, float* __restrict__ es,
    float* __restrict__ ed, int N)
{
    gemm_attn_body<K, OUTF, H, FUSE>(blockIdx.x, in, W, scale, shift,
                                     a_src, a_dst, hb, es, ed, N);
}

// Fused: first GB blocks run layer-1 gemm (seed every CU); rest do the ELL
// scatter. Scatter: 8 edges/thread (2048/block), int4 edge loads, batched
// atomics for MLP. E must be a multiple of 8 (800000 is).
template <int K, int OUTF, int H>
__global__ __launch_bounds__(256) void gemm_scatter_k(
    const int* __restrict__ ei, int* __restrict__ cur,
    unsigned short* __restrict__ colE, int E, int GB,
    const float* __restrict__ in, const float* __restrict__ W,
    const float* __restrict__ a_src, const float* __restrict__ a_dst,
    unsigned short* __restrict__ hb, float* __restrict__ es,
    float* __restrict__ ed, int N)
{
    if (blockIdx.x >= GB) {
        int e0 = (blockIdx.x - GB) * 2048 + threadIdx.x * 8;
        if (e0 + 8 <= E) {
            int4 sa = *(const int4*)(ei + e0);
            int4 sb = *(const int4*)(ei + e0 + 4);
            int4 da = *(const int4*)(ei + E + e0);
            int4 db = *(const int4*)(ei + E + e0 + 4);
            int ss[8] = {sa.x, sa.y, sa.z, sa.w, sb.x, sb.y, sb.z, sb.w};
            int dd[8] = {da.x, da.y, da.z, da.w, db.x, db.y, db.z, db.w};
            int pos[8];
#pragma unroll
            for (int u = 0; u < 8; ++u)
                pos[u] = atomicAdd(&cur[dd[u]], 1) & 63;
#pragma unroll
            for (int u = 0; u < 8; ++u)
                colE[((size_t)dd[u] << 6) + pos[u]] = (unsigned short)ss[u];
        } else {
            int i = e0 - E;   // self-loop range (E % 8 == 0 -> no straddle)
            if (i >= 0) {
#pragma unroll
                for (int u = 0; u < 8; ++u) {
                    int d = i + u;
                    if (d < N) {
                        int pos = atomicAdd(&cur[d], 1) & 63;
                        colE[((size_t)d << 6) + pos] = (unsigned short)d;
                    }
                }
            }
        }
        return;
    }
    gemm_attn_body<K, OUTF, H, false>(blockIdx.x, in, W, nullptr, nullptr,
                                      a_src, a_dst, hb, es, ed, N);
}

// ---------------------------------------------------------------------------
// Fused softmax + gather + BN partial stats. ELL rows (ushort cols):
// base = node*64, deg = cur[node] clamped to 64. LPN = H*16 lanes/node.
// First gather batch prefetched before the softmax reduce (vmcnt overlaps
// lgkmcnt shfl chain).
// ---------------------------------------------------------------------------
template <int H>
__global__ __launch_bounds__(256) void node_sg_k(
    const int* __restrict__ degA, const unsigned short* __restrict__ colE,
    const float* __restrict__ es, const float* __restrict__ ed,
    const unsigned short* __restrict__ hb, float* __restrict__ out,
    float* __restrict__ psum, float* __restrict__ psumsq, int N)
{
    constexpr int LPN = H * 16;            // 32 (H=2) or 16 (H=1)
    constexpr int F = LPN * 2;
    constexpr int NPB = 256 / LPN;
    int t = blockIdx.x * 256 + threadIdx.x;
    int node = t / LPN;
    int lane = t - node * LPN;
    const bool valid = node < N;

    const uint* h2 = (const uint*)hb;
    const float2* es2 = (const float2*)es;

    size_t base = (size_t)node << 6;
    int deg = 0;
    float ed0 = 0.f, ed1 = 0.f;
    if (valid) {
        deg = degA[node];
        if (deg > 64) deg = 64;
        if constexpr (H == 2) {
            float2 e = ((const float2*)ed)[node];
            ed0 = e.x; ed1 = e.y;
        } else {
            ed0 = ed[node];
        }
    }

    // ---- phase 1: cache first LPN edges; accumulate denominator ----
    int sc_ = 0;
    float x0 = 0.f, x1 = 0.f;
    if (lane < deg) {
        sc_ = colE[base + lane];
        if constexpr (H == 2) {
            float2 v = es2[sc_];
            x0 = __expf(lrelu(v.x + ed0));
            x1 = __expf(lrelu(v.y + ed1));
        } else {
            x0 = __expf(lrelu(es[sc_] + ed0));
        }
    }
    float s0 = x0, s1 = x1;
    for (int e = lane + LPN; e < deg; e += LPN) {
        int s = colE[base + e];
        if constexpr (H == 2) {
            float2 v = es2[s];
            s0 += __expf(lrelu(v.x + ed0));
            s1 += __expf(lrelu(v.y + ed1));
        } else {
            s0 += __expf(lrelu(es[s] + ed0));
        }
    }

    // ---- prefetch first gather batch: addresses need only sc_ ----
    const int dcap = deg < LPN ? deg : LPN;
    const bool pre = (dcap >= 8);
    int sI0[8];
    uint v0[8];
    if (pre) {
#pragma unroll
        for (int u = 0; u < 8; ++u) sI0[u] = __shfl(sc_, u, LPN);
#pragma unroll
        for (int u = 0; u < 8; ++u) v0[u] = h2[(size_t)sI0[u] * LPN + lane];
    }

    // ---- softmax reduce (shfl chain overlaps the loads above) ----
#pragma unroll
    for (int m = LPN / 2; m; m >>= 1) {
        s0 += __shfl_xor(s0, m, LPN);
        if (H == 2) s1 += __shfl_xor(s1, m, LPN);
    }
    float rd0 = 1.f / (s0 + 1e-16f);
    float rd1 = (H == 2) ? 1.f / (s1 + 1e-16f) : 0.f;

    // ---- phase 2: weighted gather (broadcast src/exp via shfl) ----
    const bool hi = (H == 2) && (lane >= 16);
    float acc0 = 0.f, acc1 = 0.f;
    int e = 0;
    if (pre) {
        float a[8];
#pragma unroll
        for (int u = 0; u < 8; ++u) {
            float a0 = __shfl(x0, u, LPN);
            if constexpr (H == 2) {
                float a1 = __shfl(x1, u, LPN);
                a[u] = hi ? a1 * rd1 : a0 * rd0;
            } else {
                a[u] = a0 * rd0;
            }
        }
#pragma unroll
        for (int u = 0; u < 8; ++u) {
            acc0 += a[u] * bf2f((unsigned short)v0[u]);
            acc1 += a[u] * bf2f((unsigned short)(v0[u] >> 16));
        }
        e = 8;
    }
    for (; e + 8 <= dcap; e += 8) {
        int sI[8];
        float a[8];
#pragma unroll
        for (int u = 0; u < 8; ++u) {
            sI[u] = __shfl(sc_, e + u, LPN);
            float a0 = __shfl(x0, e + u, LPN);
            if constexpr (H == 2) {
                float a1 = __shfl(x1, e + u, LPN);
                a[u] = hi ? a1 * rd1 : a0 * rd0;
            } else {
                a[u] = a0 * rd0;
            }
        }
        uint v[8];
#pragma unroll
        for (int u = 0; u < 8; ++u) v[u] = h2[(size_t)sI[u] * LPN + lane];
#pragma unroll
        for (int u = 0; u < 8; ++u) {
            acc0 += a[u] * bf2f((unsigned short)v[u]);
            acc1 += a[u] * bf2f((unsigned short)(v[u] >> 16));
        }
    }
    for (; e + 4 <= dcap; e += 4) {
        int sI[4];
        float a[4];
#pragma unroll
        for (int u = 0; u < 4; ++u) {
            sI[u] = __shfl(sc_, e + u, LPN);
            float a0 = __shfl(x0, e + u, LPN);
            if constexpr (H == 2) {
                float a1 = __shfl(x1, e + u, LPN);
                a[u] = hi ? a1 * rd1 : a0 * rd0;
            } else {
                a[u] = a0 * rd0;
            }
        }
        uint v[4];
#pragma unroll
        for (int u = 0; u < 4; ++u) v[u] = h2[(size_t)sI[u] * LPN + lane];
#pragma unroll
        for (int u = 0; u < 4; ++u) {
            acc0 += a[u] * bf2f((unsigned short)v[u]);
            acc1 += a[u] * bf2f((unsigned short)(v[u] >> 16));
        }
    }
    for (; e < dcap; ++e) {
        int sI = __shfl(sc_, e, LPN);
        float a0 = __shfl(x0, e, LPN);
        float a;
        if constexpr (H == 2) {
            float a1 = __shfl(x1, e, LPN);
            a = hi ? a1 * rd1 : a0 * rd0;
        } else {
            a = a0 * rd0;
        }
        uint v = h2[(size_t)sI * LPN + lane];
        acc0 += a * bf2f((unsigned short)v);
        acc1 += a * bf2f((unsigned short)(v >> 16));
    }
    for (int e2 = LPN; e2 < deg; ++e2) {       // rare tail (deg > LPN)
        int s = colE[base + e2];
        float a;
        if constexpr (H == 2) {
            float2 vv = es2[s];
            a = hi ? __expf(lrelu(vv.y + ed1)) * rd1
                   : __expf(lrelu(vv.x + ed0)) * rd0;
        } else {
            a = __expf(lrelu(es[s] + ed0)) * rd0;
        }
        uint v = h2[(size_t)s * LPN + lane];
        acc0 += a * bf2f((unsigned short)v);
        acc1 += a * bf2f((unsigned short)(v >> 16));
    }
    if (valid)
        ((float2*)out)[(size_t)node * LPN + lane] = make_float2(acc0, acc1);

    // ---- BN partial stats: block reduce, strided atomic slots ----
    __shared__ float ls0[256], ls1[256];
    ls0[threadIdx.x] = acc0;
    ls1[threadIdx.x] = acc1;
    __syncthreads();
    if (threadIdx.x < LPN) {
        int l = threadIdx.x;
        float t0 = 0.f, t0q = 0.f, t1 = 0.f, t1q = 0.f;
#pragma unroll
        for (int g = 0; g < NPB; ++g) {
            float v0_ = ls0[g * LPN + l], v1_ = ls1[g * LPN + l];
            t0 += v0_; t0q += v0_ * v0_;
            t1 += v1_; t1q += v1_ * v1_;
        }
        int slot = (blockIdx.x & 127) * F;
        atomicAdd(&psum[slot + 2 * l], t0);
        atomicAdd(&psum[slot + 2 * l + 1], t1);
        atomicAdd(&psumsq[slot + 2 * l], t0q);
        atomicAdd(&psumsq[slot + 2 * l + 1], t1q);
    }
}

// ---------------------------------------------------------------------------
// BN finalize: 256 threads = F x (256/F); LDS reduce; re-zeros partials.
// ---------------------------------------------------------------------------
__global__ void bn_final_k(float* __restrict__ psum,
                           float* __restrict__ psumsq,
                           const float* __restrict__ gamma,
                           const float* __restrict__ beta,
                           float* __restrict__ scale, float* __restrict__ shift,
                           int N, int F)
{
    int f = threadIdx.x % F;
    int r = threadIdx.x / F;
    int R = 256 / F;
    float s = 0.f, s2 = 0.f;
    for (int b = r; b < 128; b += R) {
        s += psum[b * F + f];
        s2 += psumsq[b * F + f];
        psum[b * F + f] = 0.f;
        psumsq[b * F + f] = 0.f;
    }
    __shared__ float l1[256], l2[256];
    l1[threadIdx.x] = s;
    l2[threadIdx.x] = s2;
    __syncthreads();
    if (r == 0) {
        for (int g = 1; g < R; ++g) { s += l1[g * F + f]; s2 += l2[g * F + f]; }
        float inv = 1.f / (float)N;
        float mu = s * inv;
        float var = s2 * inv - mu * mu;
        var = fmaxf(var, 0.f);
        float rs = rsqrtf(var + 1e-5f);
        float sc = rs * gamma[f];
        scale[f] = sc;
        shift[f] = beta[f] - mu * sc;
    }
}

__global__ __launch_bounds__(256) void out_final_k(
    const float* __restrict__ x, const float* __restrict__ scale,
    const float* __restrict__ shift, float* __restrict__ out, int total)
{
    int i = blockIdx.x * 256 + threadIdx.x;
    if (i >= total) return;
    int f = i & 31;
    out[i] = fmaxf(x[i] * scale[f] + shift[f], 0.f);
}

// ---------------------------------------------------------------------------

extern "C" void kernel_launch(void* const* d_in, const int* in_sizes, int n_in,
                              void* d_out, int out_size, void* d_ws,
                              size_t ws_size, hipStream_t stream)
{
    const float* x   = (const float*)d_in[0];
    const float* W1  = (const float*)d_in[1];
    const float* as1 = (const float*)d_in[2];
    const float* ad1 = (const float*)d_in[3];
    const float* g1  = (const float*)d_in[5];
    const float* be1 = (const float*)d_in[6];
    const float* W2  = (const float*)d_in[7];
    const float* as2 = (const float*)d_in[8];
    const float* ad2 = (const float*)d_in[9];
    const float* g2  = (const float*)d_in[11];
    const float* be2 = (const float*)d_in[12];
    const float* W3  = (const float*)d_in[13];
    const float* as3 = (const float*)d_in[14];
    const float* ad3 = (const float*)d_in[15];
    const float* g3  = (const float*)d_in[17];
    const float* be3 = (const float*)d_in[18];
    const int*   ei  = (const int*)d_in[19];

    const int N  = in_sizes[0] / 128;   // 50000
    const int E  = in_sizes[19] / 2;    // 800000
    const int Et = E + N;

    // Workspace layout (4-byte words). PS/PS2/cur contiguous -> one memset.
    float* ws = (float*)d_ws;
    size_t off = 0;
    unsigned short* Hb = (unsigned short*)(ws + off); off += (size_t)N * 32; // bf16 [N,64]
    float* AGG = ws + off;  off += (size_t)N * 64;
    float* ES  = ws + off;  off += (size_t)N * 2;
    float* ED  = ws + off;  off += (size_t)N * 2;
    float* SC  = ws + off;  off += 64;
    float* SH  = ws + off;  off += 64;
    size_t zOff = off;
    float* PS  = ws + off;  off += (size_t)128 * 64;  // BN partials
    float* PS2 = ws + off;  off += (size_t)128 * 64;
    int* cur   = (int*)(ws + off);  off += N;         // ELL cursor -> deg
    size_t zEnd = off;
    unsigned short* colE = (unsigned short*)(ws + off); off += (size_t)N * 32; // ushort[N*64]

    const int tiles      = (N + 63) / 64;     // 782 (M=64)
    const int gemm2Blocks = tiles * 2;        // head-split for OUTF=64
    const int gemm1Blocks = tiles;            // OUTF=32
    const int sg64Blocks = (int)(((size_t)N * 32 + 255) / 256);  // LPN=32
    const int sg32Blocks = (int)(((size_t)N * 16 + 255) / 256);  // LPN=16
    const int edgeBlocks = (Et + 2047) / 2048;   // 8 edges/thread
    const int n32Blocks  = (N * 32 + 255) / 256;

    // ---------------- init + (Layer-1 GEMM || ELL scatter) ----------------
    hipMemsetAsync(ws + zOff, 0, (zEnd - zOff) * sizeof(float), stream);
    gemm_scatter_k<128, 64, 2><<<gemm2Blocks + edgeBlocks, 256, 0, stream>>>(
        ei, cur, colE, E, gemm2Blocks,
        x, W1, as1, ad1, Hb, ES, ED, N);

    // ---------------- Layer 1 rest ----------------
    node_sg_k<2><<<sg64Blocks, 256, 0, stream>>>(cur, colE, ES, ED, Hb, AGG, PS, PS2, N);
    bn_final_k<<<1, 256, 0, stream>>>(PS, PS2, g1, be1, SC, SH, N, 64);

    // ---------------- Layer 2: 64 -> [2 x 32] ----------------
    gemm_attn_k<64, 64, 2, true><<<gemm2Blocks, 256, 0, stream>>>(
        AGG, W2, SC, SH, as2, ad2, Hb, ES, ED, N);
    node_sg_k<2><<<sg64Blocks, 256, 0, stream>>>(cur, colE, ES, ED, Hb, AGG, PS, PS2, N);
    bn_final_k<<<1, 256, 0, stream>>>(PS, PS2, g2, be2, SC, SH, N, 64);

    // ---------------- Layer 3: 64 -> [1 x 32] ----------------
    gemm_attn_k<64, 32, 1, true><<<gemm1Blocks, 256, 0, stream>>>(
        AGG, W3, SC, SH, as3, ad3, Hb, ES, ED, N);
    node_sg_k<1><<<sg32Blocks, 256, 0, stream>>>(cur, colE, ES, ED, Hb, AGG, PS, PS2, N);
    bn_final_k<<<1, 256, 0, stream>>>(PS, PS2, g3, be3, SC, SH, N, 32);
    out_final_k<<<n32Blocks, 256, 0, stream>>>(AGG, SC, SH, (float*)d_out, N * 32);
}